// Round 1
// baseline (440.985 us; speedup 1.0000x reference)
//
#include <hip/hip_runtime.h>
#include <math.h>

#define F_DIM 4096
#define BATCH 16384

typedef float f32x4 __attribute__((ext_vector_type(4)));

// Robust scalar decode: Python scalar 7 may be stored as int32/int64/fp32.
__device__ __forceinline__ int decode_nb(const void* p) {
    int i = *(const int*)p;                 // int32 / low word of int64
    if (i >= 0 && i < 1000) return i;
    float f = *(const float*)p;             // fp32 encoding
    if (f >= 0.0f && f < 1000.0f && f == floorf(f)) return (int)f;
    return 0;
}

// out[r, j] = x[r, j] * w[j] + b[nb, j]   — all fp32, elementwise.
// Grid-stride: 2048 blocks x 256 threads, 32 float4 iterations/thread.
// stride (524288) is a multiple of GROUPS_PER_ROW (1024), so each thread's
// column is loop-invariant -> w/b fragments load ONCE, then pure x-stream.
// x/out use non-temporal (nt) accesses: zero reuse, keep them out of L2.
__global__ __launch_bounds__(256) void ShareLinear_kernel(
    const f32x4* __restrict__ x,
    const f32x4* __restrict__ w,
    const float* __restrict__ b,
    const void*  __restrict__ nb,
    f32x4* __restrict__ out)
{
    constexpr int    GROUPS_PER_ROW = F_DIM / 4;                  // 1024
    constexpr size_t NGROUPS = (size_t)BATCH * F_DIM / 4;         // 16,777,216

    const size_t stride = (size_t)gridDim.x * blockDim.x;         // 524,288
    size_t gid = (size_t)blockIdx.x * blockDim.x + threadIdx.x;
    const int col = (int)(gid & (GROUPS_PER_ROW - 1));            // loop-invariant

    const int nbi = decode_nb(nb);

    const f32x4 wq = w[col];                                      // cached, reused
    const f32x4 bq = ((const f32x4*)(b + (size_t)nbi * F_DIM))[col];

    for (; gid < NGROUPS; gid += stride) {
        f32x4 xq = __builtin_nontemporal_load(&x[gid]);
        f32x4 r;
        r.x = fmaf(xq.x, wq.x, bq.x);
        r.y = fmaf(xq.y, wq.y, bq.y);
        r.z = fmaf(xq.z, wq.z, bq.z);
        r.w = fmaf(xq.w, wq.w, bq.w);
        __builtin_nontemporal_store(r, &out[gid]);
    }
}

extern "C" void kernel_launch(void* const* d_in, const int* in_sizes, int n_in,
                              void* d_out, int out_size, void* d_ws, size_t ws_size,
                              hipStream_t stream) {
    const f32x4* x = (const f32x4*)d_in[0];   // fp32 input  (16384 x 4096)
    const f32x4* w = (const f32x4*)d_in[1];   // fp32 weight (4096)
    const float* b = (const float*)d_in[2];   // fp32 bias   (1000 x 4096)
    const void* nb = d_in[3];                 // scalar

    f32x4* out = (f32x4*)d_out;               // fp32 output

    // 2048 blocks = 8 workgroups/CU on 256 CUs; grid-stride covers the rest.
    const int block = 256;
    const int grid = 2048;

    ShareLinear_kernel<<<grid, block, 0, stream>>>(x, w, b, nb, out);
}

// Round 2
// 434.130 us; speedup vs baseline: 1.0158x; 1.0158x over previous
//
#include <hip/hip_runtime.h>
#include <math.h>

#define F_DIM 4096
#define BATCH 16384

typedef float f32x4 __attribute__((ext_vector_type(4)));

// Robust scalar decode: Python scalar 7 may be stored as int32/int64/fp32.
__device__ __forceinline__ int decode_nb(const void* p) {
    int i = *(const int*)p;                 // int32 / low word of int64
    if (i >= 0 && i < 1000) return i;
    float f = *(const float*)p;             // fp32 encoding
    if (f >= 0.0f && f < 1000.0f && f == floorf(f)) return (int)f;
    return 0;
}

// out[r, j] = x[r, j] * w[j] + b[nb, j]   — all fp32, elementwise.
// One thread handles one float4 (16 B per tensor access). One-shot launch
// (65536 blocks) — known-good structure from the 424 µs baseline.
// Single isolated change vs baseline: nontemporal STORE on out (zero reuse,
// keep the 256 MiB write stream from displacing L2 lines feeding w/b).
__global__ __launch_bounds__(256) void ShareLinear_kernel(
    const f32x4* __restrict__ x,
    const f32x4* __restrict__ w,
    const float* __restrict__ b,
    const void*  __restrict__ nb,
    f32x4* __restrict__ out)
{
    constexpr int GROUPS_PER_ROW = F_DIM / 4;            // 1024 (power of two)
    const size_t gid = (size_t)blockIdx.x * blockDim.x + threadIdx.x;
    const int col = (int)(gid & (GROUPS_PER_ROW - 1));   // float4 group within row

    const int nbi = decode_nb(nb);

    const f32x4* bv = (const f32x4*)(b + (size_t)nbi * F_DIM);

    f32x4 xq = x[gid];
    f32x4 wq = w[col];    // 16 KiB total: L1/L2-resident
    f32x4 bq = bv[col];   // 16 KiB row: L1/L2-resident

    f32x4 r;
    r.x = fmaf(xq.x, wq.x, bq.x);
    r.y = fmaf(xq.y, wq.y, bq.y);
    r.z = fmaf(xq.z, wq.z, bq.z);
    r.w = fmaf(xq.w, wq.w, bq.w);

    __builtin_nontemporal_store(r, &out[gid]);
}

extern "C" void kernel_launch(void* const* d_in, const int* in_sizes, int n_in,
                              void* d_out, int out_size, void* d_ws, size_t ws_size,
                              hipStream_t stream) {
    const f32x4* x = (const f32x4*)d_in[0];   // fp32 input  (16384 x 4096)
    const f32x4* w = (const f32x4*)d_in[1];   // fp32 weight (4096)
    const float* b = (const float*)d_in[2];   // fp32 bias   (1000 x 4096)
    const void* nb = d_in[3];                 // scalar

    f32x4* out = (f32x4*)d_out;               // fp32 output

    const size_t ngroups = (size_t)BATCH * F_DIM / 4;   // 16,777,216
    const int block = 256;
    const int grid = (int)((ngroups + block - 1) / block);  // 65536 blocks

    ShareLinear_kernel<<<grid, block, 0, stream>>>(x, w, b, nb, out);
}